// Round 8
// baseline (576.155 us; speedup 1.0000x reference)
//
#include <hip/hip_runtime.h>
#include <hip/hip_bf16.h>

#define N_ROWS 16384
#define D 128
#define QBLK 256
#define KVTILE 64
#define NSPLIT 8
#define KV_PER_SPLIT (N_ROWS / NSPLIT)     // 2048
#define NT (KV_PER_SPLIT / KVTILE)         // 32
#define NTILES (N_ROWS / KVTILE)           // 256
#define LOG2E 1.4426950408889634f
#define SCALE 1.0f
#define LN_EPS 1e-5f
#define L2_EPS 1e-12f

typedef float f32x16 __attribute__((ext_vector_type(16)));
typedef short s16x8 __attribute__((ext_vector_type(8)));
typedef unsigned short u16;

__device__ __forceinline__ u16 f2bf(float f) {
    union { float f; unsigned u; } v; v.f = f;
    unsigned r = v.u + 0x7FFFu + ((v.u >> 16) & 1u);   // RNE
    return (u16)(r >> 16);
}
__device__ __forceinline__ unsigned pk2(float lo, float hi) {
    union { __hip_bfloat162 b; unsigned u; } c;
    c.b = __float22bfloat162_rn(float2{lo, hi});
    return c.u;
}
__device__ __forceinline__ float exp2_hw(float f) {
    return __builtin_amdgcn_exp2f(f);      // v_exp_f32 (base-2)
}
// L = lane-lo-half broadcast of d (L[l] = d[l&31]); H = hi-half (H[l] = d[32|(l&31)])
__device__ __forceinline__ void swap_halves(unsigned d, unsigned& L, unsigned& H) {
    unsigned a = d, b = d;
    asm volatile("v_permlane32_swap_b32 %0, %1" : "+v"(a), "+v"(b));
    L = a; H = b;
}

// ---------------- prep: invnrm[i] = 1 / max(||x_i||, eps) ----------------
__global__ __launch_bounds__(256) void prep_norms(const float* __restrict__ x,
                                                  float* __restrict__ invnrm) {
    int t = threadIdx.x;
    int row = blockIdx.x * 64 + (t >> 2);
    int q = t & 3;
    const float4* xr = (const float4*)(x + (size_t)row * D);
    float s = 0.f;
#pragma unroll
    for (int i = 0; i < 8; ++i) {
        float4 v = xr[q * 8 + i];
        s += v.x * v.x + v.y * v.y + v.z * v.z + v.w * v.w;
    }
    s += __shfl_xor(s, 1);
    s += __shfl_xor(s, 2);
    if (q == 0) invnrm[row] = 1.0f / fmaxf(sqrtf(s), L2_EPS);
}

// Kimg: row-major bf16 of normalized x (16384 x 128). Chunk ch (16B) = 8 elems.
__global__ __launch_bounds__(256) void prep_imgK(const float* __restrict__ x,
                                                 const float* __restrict__ invnrm,
                                                 u16* __restrict__ Kimg) {
    int c = blockIdx.x * 256 + threadIdx.x;       // chunk id, 0..262143
    int kv = c >> 4;
    int lc = c & 15;
    const float* p = x + (size_t)kv * D + 8 * lc;
    float inv = invnrm[kv];
    float4 a = *(const float4*)p;
    float4 b = *(const float4*)(p + 4);
    union { unsigned u[4]; s16x8 v; } pk;
    pk.u[0] = pk2(a.x * inv, a.y * inv);
    pk.u[1] = pk2(a.z * inv, a.w * inv);
    pk.u[2] = pk2(b.x * inv, b.y * inv);
    pk.u[3] = pk2(b.z * inv, b.w * inv);
    *(s16x8*)(Kimg + (size_t)c * 8) = pk.v;
}

// VTimg per tile (16 KB): chunk (r 0..63, cc 0..15) holds V^T:
//   d = 2r + (cc>>3); elements e=0..7 -> bf16(x[64*tile + 8*(cc&7) + e][d]).
__global__ __launch_bounds__(256) void prep_imgVT(const float* __restrict__ x,
                                                  u16* __restrict__ VTimg) {
    __shared__ float sx[KVTILE][D + 4];           // stride 132 floats
    int tile = blockIdx.x;
    int tid = threadIdx.x;
#pragma unroll
    for (int j = 0; j < 8; ++j) {
        int idx = j * 1024 + tid * 4;
        int r = idx >> 7, cc = idx & 127;
        *(float4*)&sx[r][cc] = *(const float4*)(x + (size_t)(tile * 64 + r) * D + cc);
    }
    __syncthreads();
#pragma unroll
    for (int j = 0; j < 4; ++j) {
        int ch = j * 256 + tid;                   // 0..1023
        int r = ch >> 4, cc = ch & 15;
        int d = 2 * r + (cc >> 3);
        int kv0 = 8 * (cc & 7);
        union { u16 s[8]; s16x8 v; } pk;
#pragma unroll
        for (int e = 0; e < 8; ++e) pk.s[e] = f2bf(sx[kv0 + e][d]);
        *(s16x8*)(VTimg + (size_t)tile * 8192 + (size_t)ch * 8) = pk.v;
    }
}

// 4 waves x 64 q-rows; 2 waves/SIMD (256-reg budget: 128 acc + ~68 arch fits)
__global__ __launch_bounds__(256, 2) void attn(const float* __restrict__ x,
                                               const u16* __restrict__ Kimg,
                                               const u16* __restrict__ VTimg,
                                               const float* __restrict__ invnrm,
                                               float* __restrict__ num,
                                               float* __restrict__ denom) {
    __shared__ __align__(16) u16 sK[2][KVTILE * D];   // 2 x 16 KB
    __shared__ __align__(16) u16 sV[2][KVTILE * D];   // 2 x 16 KB

    const int bx = blockIdx.x;
    const int qb = bx >> 3;
    const int sp = bx & 7;                  // XCD under %8 round-robin
    const int qrow0 = qb * QBLK;
    const int tile0 = sp * NT;

    const int tid = threadIdx.x;
    const int w = tid >> 6;                 // 4 waves, 64 q-rows each
    const int lane = tid & 63;
    const int h = lane >> 5;
    const int ln5 = lane & 31;

    // --- Q B-fragments in registers, scaled by invnrm * log2e ---
    s16x8 qf[2][8];
#pragma unroll
    for (int rt = 0; rt < 2; ++rt) {
        const int q = qrow0 + 64 * w + 32 * rt + ln5;
        const float sc = invnrm[q] * LOG2E;
#pragma unroll
        for (int ks = 0; ks < 8; ++ks) {
            const float* p = x + (size_t)q * D + 16 * ks + 8 * h;
            float4 a = *(const float4*)p;
            float4 b = *(const float4*)(p + 4);
            union { unsigned u[4]; s16x8 v; } pk;
            pk.u[0] = pk2(a.x * sc, a.y * sc);
            pk.u[1] = pk2(a.z * sc, a.w * sc);
            pk.u[2] = pk2(b.x * sc, b.y * sc);
            pk.u[3] = pk2(b.z * sc, b.w * sc);
            qf[rt][ks] = pk.v;
        }
    }

    f32x16 acc[2][4];
#pragma unroll
    for (int rt = 0; rt < 2; ++rt)
#pragma unroll
        for (int dt = 0; dt < 4; ++dt)
#pragma unroll
            for (int r = 0; r < 16; ++r) acc[rt][dt][r] = 0.f;
    float rowsum[2] = {0.f, 0.f};

    // ---- staging: global (bf16 images) -> regs -> swizzled LDS ----
    s16x8 kst[4], vst[4];
    auto stage_load = [&](int t) {
        const s16x8* kt = (const s16x8*)(Kimg + (size_t)(tile0 + t) * 8192);
        const s16x8* vt = (const s16x8*)(VTimg + (size_t)(tile0 + t) * 8192);
#pragma unroll
        for (int j = 0; j < 4; ++j) {
            kst[j] = kt[j * 256 + tid];
            vst[j] = vt[j * 256 + tid];
        }
    };
    auto stage_write = [&](int buf) {
#pragma unroll
        for (int j = 0; j < 4; ++j) {
            int ch = j * 256 + tid;
            int row = ch >> 4, c16 = ch & 15;
            *(s16x8*)((char*)sK[buf] + row * 256 + 16 * (c16 ^ (row & 15))) = kst[j];
            *(s16x8*)((char*)sV[buf] + row * 256 + 16 * ((c16 + row) & 15)) = vst[j];
        }
    };

    stage_load(0);
    stage_write(0);
    __syncthreads();

    for (int tile = 0; tile < NT; ++tile) {
        const int cur = tile & 1;
        const bool pf = (tile + 1 < NT);
        if (pf) stage_load(tile + 1);       // issue early; lands under compute

        const u16* bK = sK[cur];
        const u16* bV = sV[cur];

#pragma unroll
        for (int ct = 0; ct < 2; ++ct) {
            const char* krow = (const char*)bK + (32 * ct + ln5) * 256;
            // ---- S^T = K Qn^T over d=128, kf shared across rt ----
            f32x16 s[2];
#pragma unroll
            for (int r = 0; r < 16; ++r) { s[0][r] = 0.f; s[1][r] = 0.f; }
            __builtin_amdgcn_s_setprio(1);
#pragma unroll
            for (int ks = 0; ks < 8; ++ks) {
                s16x8 kf = *(const s16x8*)(krow + 16 * ((2 * ks + h) ^ (ln5 & 15)));
                s[0] = __builtin_amdgcn_mfma_f32_32x32x16_bf16(kf, qf[0][ks], s[0], 0, 0, 0);
                s[1] = __builtin_amdgcn_mfma_f32_32x32x16_bf16(kf, qf[1][ks], s[1], 0, 0, 0);
            }
            __builtin_amdgcn_s_setprio(0);

            // ---- P = exp2(S); half-exchange via permlane (VALU, not DS pipe) ----
            unsigned A[2][2][4];            // [rt][kt2][dword]
#pragma unroll
            for (int rt = 0; rt < 2; ++rt) {
                unsigned L0[4], H0[4], L1[4], H1[4];
#pragma unroll
                for (int m = 0; m < 4; ++m) {
                    float p0 = exp2_hw(s[rt][4 * m + 0]);
                    float p1 = exp2_hw(s[rt][4 * m + 1]);
                    float p2 = exp2_hw(s[rt][4 * m + 2]);
                    float p3 = exp2_hw(s[rt][4 * m + 3]);
                    rowsum[rt] += (p0 + p1) + (p2 + p3);
                    swap_halves(pk2(p0, p1), L0[m], H0[m]);
                    swap_halves(pk2(p2, p3), L1[m], H1[m]);
                }
#pragma unroll
                for (int kt2 = 0; kt2 < 2; ++kt2) {
                    A[rt][kt2][0] = h ? L0[2 * kt2 + 1] : L0[2 * kt2];
                    A[rt][kt2][1] = h ? L1[2 * kt2 + 1] : L1[2 * kt2];
                    A[rt][kt2][2] = h ? H0[2 * kt2 + 1] : H0[2 * kt2];
                    A[rt][kt2][3] = h ? H1[2 * kt2 + 1] : H1[2 * kt2];
                }
            }

            // ---- O += P V, vf shared across rt ----
#pragma unroll
            for (int kt2 = 0; kt2 < 2; ++kt2) {
                union { unsigned u[4]; s16x8 v; } Au0, Au1;
#pragma unroll
                for (int m = 0; m < 4; ++m) {
                    Au0.u[m] = A[0][kt2][m];
                    Au1.u[m] = A[1][kt2][m];
                }
                const int ktg = 2 * ct + kt2;
                const int ccv = (8 * (ln5 & 1) + 2 * ktg + h + (ln5 >> 1)) & 15;
                __builtin_amdgcn_s_setprio(1);
#pragma unroll
                for (int dt = 0; dt < 4; ++dt) {
                    s16x8 vf = *(const s16x8*)((const char*)bV +
                                               (16 * dt + (ln5 >> 1)) * 256 + 16 * ccv);
                    acc[0][dt] = __builtin_amdgcn_mfma_f32_32x32x16_bf16(Au0.v, vf, acc[0][dt], 0, 0, 0);
                    acc[1][dt] = __builtin_amdgcn_mfma_f32_32x32x16_bf16(Au1.v, vf, acc[1][dt], 0, 0, 0);
                }
                __builtin_amdgcn_s_setprio(0);
            }
        }

        if (pf) stage_write(cur ^ 1);       // write late (T14), then one barrier
        __syncthreads();
    }

    // ---- epilogue: combine partials via device-scope atomics ----
#pragma unroll
    for (int rt = 0; rt < 2; ++rt) {
        float tot = rowsum[rt] + __shfl_xor(rowsum[rt], 32);
        if (h == 0) atomicAdd(&denom[qrow0 + 64 * w + 32 * rt + ln5], tot);
    }
#pragma unroll
    for (int rt = 0; rt < 2; ++rt)
#pragma unroll
        for (int dt = 0; dt < 4; ++dt)
#pragma unroll
            for (int r = 0; r < 16; ++r) {
                int qr = qrow0 + 64 * w + 32 * rt + (r & 3) + 8 * (r >> 2) + 4 * h;
                atomicAdd(&num[(size_t)qr * D + 32 * dt + ln5], acc[rt][dt][r]);
            }
}

// ---------------- finalize: y = 2x - num/denom ; LayerNorm ----------------
__global__ __launch_bounds__(256) void finalize(const float* __restrict__ x,
                                                const float* __restrict__ gamma,
                                                const float* __restrict__ beta,
                                                const float* __restrict__ denom,
                                                float* __restrict__ out) {  // out == num, in place
    int t = threadIdx.x;
    int row = blockIdx.x * 64 + (t >> 2);
    int q = t & 3;
    float invd = 1.0f / denom[row];
    const float4* xr = (const float4*)(x + (size_t)row * D);
    const float4* nr = (const float4*)(out + (size_t)row * D);
    float y[32];
    float s1 = 0.f, s2 = 0.f;
#pragma unroll
    for (int i = 0; i < 8; ++i) {
        float4 xv = xr[q * 8 + i];
        float4 nv = nr[q * 8 + i];
#pragma unroll
        for (int j = 0; j < 4; ++j) {
            float yv = (1.0f + SCALE) * (&xv.x)[j] - SCALE * ((&nv.x)[j] * invd);
            y[i * 4 + j] = yv;
            s1 += yv;
            s2 += yv * yv;
        }
    }
    s1 += __shfl_xor(s1, 1); s1 += __shfl_xor(s1, 2);
    s2 += __shfl_xor(s2, 1); s2 += __shfl_xor(s2, 2);
    float mu = s1 * (1.0f / D);
    float var = s2 * (1.0f / D) - mu * mu;
    float rstd = rsqrtf(var + LN_EPS);
    float4* orow = (float4*)(out + (size_t)row * D);
#pragma unroll
    for (int i = 0; i < 8; ++i) {
        int c = q * 32 + i * 4;
        float4 o;
#pragma unroll
        for (int j = 0; j < 4; ++j)
            (&o.x)[j] = (y[i * 4 + j] - mu) * rstd * gamma[c + j] + beta[c + j];
        orow[q * 8 + i] = o;
    }
}

extern "C" void kernel_launch(void* const* d_in, const int* in_sizes, int n_in,
                              void* d_out, int out_size, void* d_ws, size_t ws_size,
                              hipStream_t stream) {
    const float* x = (const float*)d_in[0];
    const float* gamma = (const float*)d_in[1];
    const float* beta = (const float*)d_in[2];
    float* out = (float*)d_out;

    float* invnrm = (float*)d_ws;                       // 64 KB
    float* denom = invnrm + N_ROWS;                     // 64 KB
    u16* Kimg = (u16*)(denom + N_ROWS);                 // 4 MB
    u16* VTimg = Kimg + (size_t)NTILES * 8192;          // 4 MB  (total ~8.4 MB)

    (void)hipMemsetAsync(d_out, 0, (size_t)N_ROWS * D * sizeof(float), stream);  // num accumulator
    (void)hipMemsetAsync(denom, 0, (size_t)N_ROWS * sizeof(float), stream);

    prep_norms<<<N_ROWS / 64, 256, 0, stream>>>(x, invnrm);
    prep_imgK<<<NTILES * 4, 256, 0, stream>>>(x, invnrm, Kimg);
    prep_imgVT<<<NTILES, 256, 0, stream>>>(x, VTimg);
    attn<<<(N_ROWS / QBLK) * NSPLIT, 256, 0, stream>>>(x, Kimg, VTimg, invnrm, out, denom);
    finalize<<<N_ROWS / 64, 256, 0, stream>>>(x, gamma, beta, denom, out);
}

// Round 9
// 219.100 us; speedup vs baseline: 2.6296x; 2.6296x over previous
//
#include <hip/hip_runtime.h>
#include <hip/hip_bf16.h>

#define N_ROWS 16384
#define D 128
#define QBLK 256
#define KVTILE 64
#define NSPLIT 8
#define KV_PER_SPLIT (N_ROWS / NSPLIT)     // 2048
#define NT (KV_PER_SPLIT / KVTILE)         // 32
#define NTILES (N_ROWS / KVTILE)           // 256
#define LOG2E 1.4426950408889634f
#define SCALE 1.0f
#define LN_EPS 1e-5f
#define L2_EPS 1e-12f

typedef float f32x16 __attribute__((ext_vector_type(16)));
typedef short s16x8 __attribute__((ext_vector_type(8)));
typedef unsigned short u16;

__device__ __forceinline__ u16 f2bf(float f) {
    union { float f; unsigned u; } v; v.f = f;
    unsigned r = v.u + 0x7FFFu + ((v.u >> 16) & 1u);   // RNE
    return (u16)(r >> 16);
}
__device__ __forceinline__ unsigned pk2(float lo, float hi) {
    union { __hip_bfloat162 b; unsigned u; } c;
    c.b = __float22bfloat162_rn(float2{lo, hi});
    return c.u;
}
__device__ __forceinline__ float exp2_hw(float f) {
    return __builtin_amdgcn_exp2f(f);      // v_exp_f32 (base-2)
}
// L = lane-lo-half broadcast of d (L[l] = d[l&31]); H = hi-half (H[l] = d[32|(l&31)])
__device__ __forceinline__ void swap_halves(unsigned d, unsigned& L, unsigned& H) {
    unsigned a = d, b = d;
    asm volatile("v_permlane32_swap_b32 %0, %1" : "+v"(a), "+v"(b));
    L = a; H = b;
}

// ---------------- prep: invnrm[i] = 1 / max(||x_i||, eps) ----------------
__global__ __launch_bounds__(256) void prep_norms(const float* __restrict__ x,
                                                  float* __restrict__ invnrm) {
    int t = threadIdx.x;
    int row = blockIdx.x * 64 + (t >> 2);
    int q = t & 3;
    const float4* xr = (const float4*)(x + (size_t)row * D);
    float s = 0.f;
#pragma unroll
    for (int i = 0; i < 8; ++i) {
        float4 v = xr[q * 8 + i];
        s += v.x * v.x + v.y * v.y + v.z * v.z + v.w * v.w;
    }
    s += __shfl_xor(s, 1);
    s += __shfl_xor(s, 2);
    if (q == 0) invnrm[row] = 1.0f / fmaxf(sqrtf(s), L2_EPS);
}

// Kimg: row-major bf16 of normalized x (16384 x 128). Chunk ch (16B) = 8 elems.
__global__ __launch_bounds__(256) void prep_imgK(const float* __restrict__ x,
                                                 const float* __restrict__ invnrm,
                                                 u16* __restrict__ Kimg) {
    int c = blockIdx.x * 256 + threadIdx.x;       // chunk id, 0..262143
    int kv = c >> 4;
    int lc = c & 15;
    const float* p = x + (size_t)kv * D + 8 * lc;
    float inv = invnrm[kv];
    float4 a = *(const float4*)p;
    float4 b = *(const float4*)(p + 4);
    union { unsigned u[4]; s16x8 v; } pk;
    pk.u[0] = pk2(a.x * inv, a.y * inv);
    pk.u[1] = pk2(a.z * inv, a.w * inv);
    pk.u[2] = pk2(b.x * inv, b.y * inv);
    pk.u[3] = pk2(b.z * inv, b.w * inv);
    *(s16x8*)(Kimg + (size_t)c * 8) = pk.v;
}

// VTimg per tile (16 KB): chunk (r 0..63, cc 0..15) holds V^T:
//   d = 2r + (cc>>3); elements e=0..7 -> bf16(x[64*tile + 8*(cc&7) + e][d]).
__global__ __launch_bounds__(256) void prep_imgVT(const float* __restrict__ x,
                                                  u16* __restrict__ VTimg) {
    __shared__ float sx[KVTILE][D + 4];           // stride 132 floats
    int tile = blockIdx.x;
    int tid = threadIdx.x;
#pragma unroll
    for (int j = 0; j < 8; ++j) {
        int idx = j * 1024 + tid * 4;
        int r = idx >> 7, cc = idx & 127;
        *(float4*)&sx[r][cc] = *(const float4*)(x + (size_t)(tile * 64 + r) * D + cc);
    }
    __syncthreads();
#pragma unroll
    for (int j = 0; j < 4; ++j) {
        int ch = j * 256 + tid;                   // 0..1023
        int r = ch >> 4, cc = ch & 15;
        int d = 2 * r + (cc >> 3);
        int kv0 = 8 * (cc & 7);
        union { u16 s[8]; s16x8 v; } pk;
#pragma unroll
        for (int e = 0; e < 8; ++e) pk.s[e] = f2bf(sx[kv0 + e][d]);
        *(s16x8*)(VTimg + (size_t)tile * 8192 + (size_t)ch * 8) = pk.v;
    }
}

// 8 waves x 32 q-rows; 2 waves/SIMD (256-reg budget; peak live ~195 regs)
__global__ __launch_bounds__(512, 2) void attn(const float* __restrict__ x,
                                               const u16* __restrict__ Kimg,
                                               const u16* __restrict__ VTimg,
                                               const float* __restrict__ invnrm,
                                               float* __restrict__ num,
                                               float* __restrict__ denom) {
    __shared__ __align__(16) u16 sK[2][KVTILE * D];   // 2 x 16 KB
    __shared__ __align__(16) u16 sV[2][KVTILE * D];   // 2 x 16 KB

    const int bx = blockIdx.x;
    const int qb = bx >> 3;
    const int sp = bx & 7;                  // XCD under %8 round-robin
    const int qrow0 = qb * QBLK;
    const int tile0 = sp * NT;

    const int tid = threadIdx.x;
    const int w = tid >> 6;                 // 8 waves, 32 q-rows each
    const int lane = tid & 63;
    const int h = lane >> 5;
    const int ln5 = lane & 31;

    // --- Q B-fragments in registers, scaled by invnrm * log2e ---
    const int q = qrow0 + 32 * w + ln5;
    const float sc = invnrm[q] * LOG2E;
    s16x8 qf[8];
#pragma unroll
    for (int ks = 0; ks < 8; ++ks) {
        const float* p = x + (size_t)q * D + 16 * ks + 8 * h;
        float4 a = *(const float4*)p;
        float4 b = *(const float4*)(p + 4);
        union { unsigned u[4]; s16x8 v; } pk;
        pk.u[0] = pk2(a.x * sc, a.y * sc);
        pk.u[1] = pk2(a.z * sc, a.w * sc);
        pk.u[2] = pk2(b.x * sc, b.y * sc);
        pk.u[3] = pk2(b.z * sc, b.w * sc);
        qf[ks] = pk.v;
    }

    f32x16 acc[4];
#pragma unroll
    for (int dt = 0; dt < 4; ++dt)
#pragma unroll
        for (int r = 0; r < 16; ++r) acc[dt][r] = 0.f;
    float rowsum = 0.f;

    // ---- staging: global (bf16 images) -> regs -> swizzled LDS ----
    s16x8 kst[2], vst[2];
    auto stage_load = [&](int t) {
        const s16x8* kt = (const s16x8*)(Kimg + (size_t)(tile0 + t) * 8192);
        const s16x8* vt = (const s16x8*)(VTimg + (size_t)(tile0 + t) * 8192);
#pragma unroll
        for (int j = 0; j < 2; ++j) {
            kst[j] = kt[j * 512 + tid];
            vst[j] = vt[j * 512 + tid];
        }
    };
    auto stage_write = [&](int buf) {
#pragma unroll
        for (int j = 0; j < 2; ++j) {
            int ch = j * 512 + tid;
            int row = ch >> 4, c16 = ch & 15;
            *(s16x8*)((char*)sK[buf] + row * 256 + 16 * (c16 ^ (row & 15))) = kst[j];
            *(s16x8*)((char*)sV[buf] + row * 256 + 16 * ((c16 + row) & 15)) = vst[j];
        }
    };

    stage_load(0);
    stage_write(0);
    __syncthreads();

    for (int tile = 0; tile < NT; ++tile) {
        const int cur = tile & 1;
        const bool pf = (tile + 1 < NT);
        if (pf) stage_load(tile + 1);       // issue early; lands under compute

        const u16* bK = sK[cur];
        const u16* bV = sV[cur];

#pragma unroll
        for (int ct = 0; ct < 2; ++ct) {
            const char* krow = (const char*)bK + (32 * ct + ln5) * 256;
            // ---- S^T = K Qn^T over d=128, two interleaved partial chains ----
            f32x16 sa, sb;
#pragma unroll
            for (int r = 0; r < 16; ++r) { sa[r] = 0.f; sb[r] = 0.f; }
            __builtin_amdgcn_s_setprio(1);
#pragma unroll
            for (int ks = 0; ks < 8; ks += 2) {
                s16x8 kf0 = *(const s16x8*)(krow + 16 * ((2 * ks + h) ^ (ln5 & 15)));
                s16x8 kf1 = *(const s16x8*)(krow + 16 * ((2 * ks + 2 + h) ^ (ln5 & 15)));
                sa = __builtin_amdgcn_mfma_f32_32x32x16_bf16(kf0, qf[ks], sa, 0, 0, 0);
                sb = __builtin_amdgcn_mfma_f32_32x32x16_bf16(kf1, qf[ks + 1], sb, 0, 0, 0);
            }
            __builtin_amdgcn_s_setprio(0);

            // ---- P = exp2(sa+sb); half-exchange via permlane (VALU pipe) ----
            unsigned L0[4], H0[4], L1[4], H1[4];
#pragma unroll
            for (int m = 0; m < 4; ++m) {
                float p0 = exp2_hw(sa[4 * m + 0] + sb[4 * m + 0]);
                float p1 = exp2_hw(sa[4 * m + 1] + sb[4 * m + 1]);
                float p2 = exp2_hw(sa[4 * m + 2] + sb[4 * m + 2]);
                float p3 = exp2_hw(sa[4 * m + 3] + sb[4 * m + 3]);
                rowsum += (p0 + p1) + (p2 + p3);
                swap_halves(pk2(p0, p1), L0[m], H0[m]);
                swap_halves(pk2(p2, p3), L1[m], H1[m]);
            }

            // ---- O += P V ----
#pragma unroll
            for (int kt2 = 0; kt2 < 2; ++kt2) {
                union { unsigned u[4]; s16x8 v; } Au;
                Au.u[0] = h ? L0[2 * kt2 + 1] : L0[2 * kt2];
                Au.u[1] = h ? L1[2 * kt2 + 1] : L1[2 * kt2];
                Au.u[2] = h ? H0[2 * kt2 + 1] : H0[2 * kt2];
                Au.u[3] = h ? H1[2 * kt2 + 1] : H1[2 * kt2];
                const int ktg = 2 * ct + kt2;
                const int ccv = (8 * (ln5 & 1) + 2 * ktg + h + (ln5 >> 1)) & 15;
                __builtin_amdgcn_s_setprio(1);
#pragma unroll
                for (int dt = 0; dt < 4; ++dt) {
                    s16x8 vf = *(const s16x8*)((const char*)bV +
                                               (16 * dt + (ln5 >> 1)) * 256 + 16 * ccv);
                    acc[dt] = __builtin_amdgcn_mfma_f32_32x32x16_bf16(Au.v, vf, acc[dt], 0, 0, 0);
                }
                __builtin_amdgcn_s_setprio(0);
            }
        }

        if (pf) stage_write(cur ^ 1);       // write late (T14), then one barrier
        __syncthreads();
    }

    // ---- epilogue: combine partials via device-scope atomics ----
    float tot = rowsum + __shfl_xor(rowsum, 32);
    if (h == 0) atomicAdd(&denom[q], tot);
#pragma unroll
    for (int dt = 0; dt < 4; ++dt)
#pragma unroll
        for (int r = 0; r < 16; ++r) {
            int qr = qrow0 + 32 * w + (r & 3) + 8 * (r >> 2) + 4 * h;
            atomicAdd(&num[(size_t)qr * D + 32 * dt + ln5], acc[dt][r]);
        }
}

// ---------------- finalize: y = 2x - num/denom ; LayerNorm ----------------
__global__ __launch_bounds__(256) void finalize(const float* __restrict__ x,
                                                const float* __restrict__ gamma,
                                                const float* __restrict__ beta,
                                                const float* __restrict__ denom,
                                                float* __restrict__ out) {  // out == num, in place
    int t = threadIdx.x;
    int row = blockIdx.x * 64 + (t >> 2);
    int q = t & 3;
    float invd = 1.0f / denom[row];
    const float4* xr = (const float4*)(x + (size_t)row * D);
    const float4* nr = (const float4*)(out + (size_t)row * D);
    float y[32];
    float s1 = 0.f, s2 = 0.f;
#pragma unroll
    for (int i = 0; i < 8; ++i) {
        float4 xv = xr[q * 8 + i];
        float4 nv = nr[q * 8 + i];
#pragma unroll
        for (int j = 0; j < 4; ++j) {
            float yv = (1.0f + SCALE) * (&xv.x)[j] - SCALE * ((&nv.x)[j] * invd);
            y[i * 4 + j] = yv;
            s1 += yv;
            s2 += yv * yv;
        }
    }
    s1 += __shfl_xor(s1, 1); s1 += __shfl_xor(s1, 2);
    s2 += __shfl_xor(s2, 1); s2 += __shfl_xor(s2, 2);
    float mu = s1 * (1.0f / D);
    float var = s2 * (1.0f / D) - mu * mu;
    float rstd = rsqrtf(var + LN_EPS);
    float4* orow = (float4*)(out + (size_t)row * D);
#pragma unroll
    for (int i = 0; i < 8; ++i) {
        int c = q * 32 + i * 4;
        float4 o;
#pragma unroll
        for (int j = 0; j < 4; ++j)
            (&o.x)[j] = (y[i * 4 + j] - mu) * rstd * gamma[c + j] + beta[c + j];
        orow[q * 8 + i] = o;
    }
}

extern "C" void kernel_launch(void* const* d_in, const int* in_sizes, int n_in,
                              void* d_out, int out_size, void* d_ws, size_t ws_size,
                              hipStream_t stream) {
    const float* x = (const float*)d_in[0];
    const float* gamma = (const float*)d_in[1];
    const float* beta = (const float*)d_in[2];
    float* out = (float*)d_out;

    float* invnrm = (float*)d_ws;                       // 64 KB
    float* denom = invnrm + N_ROWS;                     // 64 KB
    u16* Kimg = (u16*)(denom + N_ROWS);                 // 4 MB
    u16* VTimg = Kimg + (size_t)NTILES * 8192;          // 4 MB  (total ~8.4 MB)

    (void)hipMemsetAsync(d_out, 0, (size_t)N_ROWS * D * sizeof(float), stream);  // num accumulator
    (void)hipMemsetAsync(denom, 0, (size_t)N_ROWS * sizeof(float), stream);

    prep_norms<<<N_ROWS / 64, 256, 0, stream>>>(x, invnrm);
    prep_imgK<<<NTILES * 4, 256, 0, stream>>>(x, invnrm, Kimg);
    prep_imgVT<<<NTILES, 256, 0, stream>>>(x, VTimg);
    attn<<<(N_ROWS / QBLK) * NSPLIT, 512, 0, stream>>>(x, Kimg, VTimg, invnrm, out, denom);
    finalize<<<N_ROWS / 64, 256, 0, stream>>>(x, gamma, beta, denom, out);
}

// Round 10
// 194.270 us; speedup vs baseline: 2.9657x; 1.1278x over previous
//
#include <hip/hip_runtime.h>
#include <hip/hip_bf16.h>

#define N_ROWS 16384
#define D 128
#define QBLK 256
#define KVTILE 64
#define NSPLIT 4
#define KV_PER_SPLIT (N_ROWS / NSPLIT)     // 4096
#define NT (KV_PER_SPLIT / KVTILE)         // 64
#define NTILES (N_ROWS / KVTILE)           // 256
#define LOG2E 1.4426950408889634f
#define SCALE 1.0f
#define LN_EPS 1e-5f
#define L2_EPS 1e-12f

typedef float f32x16 __attribute__((ext_vector_type(16)));
typedef short s16x8 __attribute__((ext_vector_type(8)));
typedef unsigned short u16;

__device__ __forceinline__ u16 f2bf(float f) {
    union { float f; unsigned u; } v; v.f = f;
    unsigned r = v.u + 0x7FFFu + ((v.u >> 16) & 1u);   // RNE
    return (u16)(r >> 16);
}
__device__ __forceinline__ unsigned pk2(float lo, float hi) {
    union { __hip_bfloat162 b; unsigned u; } c;
    c.b = __float22bfloat162_rn(float2{lo, hi});
    return c.u;
}
__device__ __forceinline__ float exp2_hw(float f) {
    return __builtin_amdgcn_exp2f(f);      // v_exp_f32 (base-2)
}

// ---------------- prep: invnrm[i] = 1 / max(||x_i||, eps) ----------------
__global__ __launch_bounds__(256) void prep_norms(const float* __restrict__ x,
                                                  float* __restrict__ invnrm) {
    int t = threadIdx.x;
    int row = blockIdx.x * 64 + (t >> 2);
    int q = t & 3;
    const float4* xr = (const float4*)(x + (size_t)row * D);
    float s = 0.f;
#pragma unroll
    for (int i = 0; i < 8; ++i) {
        float4 v = xr[q * 8 + i];
        s += v.x * v.x + v.y * v.y + v.z * v.z + v.w * v.w;
    }
    s += __shfl_xor(s, 1);
    s += __shfl_xor(s, 2);
    if (q == 0) invnrm[row] = 1.0f / fmaxf(sqrtf(s), L2_EPS);
}

// Kimg: row-major bf16 of normalized x (16384 x 128). Chunk ch (16B) = 8 elems.
__global__ __launch_bounds__(256) void prep_imgK(const float* __restrict__ x,
                                                 const float* __restrict__ invnrm,
                                                 u16* __restrict__ Kimg) {
    int c = blockIdx.x * 256 + threadIdx.x;       // chunk id, 0..262143
    int kv = c >> 4;
    int lc = c & 15;
    const float* p = x + (size_t)kv * D + 8 * lc;
    float inv = invnrm[kv];
    float4 a = *(const float4*)p;
    float4 b = *(const float4*)(p + 4);
    union { unsigned u[4]; s16x8 v; } pk;
    pk.u[0] = pk2(a.x * inv, a.y * inv);
    pk.u[1] = pk2(a.z * inv, a.w * inv);
    pk.u[2] = pk2(b.x * inv, b.y * inv);
    pk.u[3] = pk2(b.z * inv, b.w * inv);
    *(s16x8*)(Kimg + (size_t)c * 8) = pk.v;
}

// VTimg per tile (16 KB): chunk (r 0..63, cc 0..15) holds V^T:
//   d = 2r + (cc>>3); elements e=0..7 -> bf16(x[64*tile + 8*(cc&7) + e][d]).
__global__ __launch_bounds__(256) void prep_imgVT(const float* __restrict__ x,
                                                  u16* __restrict__ VTimg) {
    __shared__ float sx[KVTILE][D + 4];           // stride 132 floats
    int tile = blockIdx.x;
    int tid = threadIdx.x;
#pragma unroll
    for (int j = 0; j < 8; ++j) {
        int idx = j * 1024 + tid * 4;
        int r = idx >> 7, cc = idx & 127;
        *(float4*)&sx[r][cc] = *(const float4*)(x + (size_t)(tile * 64 + r) * D + cc);
    }
    __syncthreads();
#pragma unroll
    for (int j = 0; j < 4; ++j) {
        int ch = j * 256 + tid;                   // 0..1023
        int r = ch >> 4, cc = ch & 15;
        int d = 2 * r + (cc >> 3);
        int kv0 = 8 * (cc & 7);
        union { u16 s[8]; s16x8 v; } pk;
#pragma unroll
        for (int e = 0; e < 8; ++e) pk.s[e] = f2bf(sx[kv0 + e][d]);
        *(s16x8*)(VTimg + (size_t)tile * 8192 + (size_t)ch * 8) = pk.v;
    }
}

// 8 waves x 32 q-rows; 2 waves/SIMD; grid 256 = 1 block/CU
__global__ __launch_bounds__(512, 2) void attn(const float* __restrict__ x,
                                               const u16* __restrict__ Kimg,
                                               const u16* __restrict__ VTimg,
                                               const float* __restrict__ invnrm,
                                               float* __restrict__ num,
                                               float* __restrict__ denom) {
    __shared__ __align__(16) u16 sK[2][KVTILE * D];   // 2 x 16 KB
    __shared__ __align__(16) u16 sV[2][KVTILE * D];   // 2 x 16 KB

    const int bx = blockIdx.x;
    const int qb = bx >> 2;
    const int sp = bx & 3;                  // split; bx&7 keeps XCD locality
    const int qrow0 = qb * QBLK;
    const int tile0 = sp * NT;

    const int tid = threadIdx.x;
    const int w = tid >> 6;                 // 8 waves, 32 q-rows each
    const int lane = tid & 63;
    const int h = lane >> 5;
    const int ln5 = lane & 31;

    // --- Q B-fragments in registers, scaled by invnrm * log2e ---
    const int q = qrow0 + 32 * w + ln5;
    const float sc = invnrm[q] * LOG2E;
    s16x8 qf[8];
#pragma unroll
    for (int ks = 0; ks < 8; ++ks) {
        const float* p = x + (size_t)q * D + 16 * ks + 8 * h;
        float4 a = *(const float4*)p;
        float4 b = *(const float4*)(p + 4);
        union { unsigned u[4]; s16x8 v; } pk;
        pk.u[0] = pk2(a.x * sc, a.y * sc);
        pk.u[1] = pk2(a.z * sc, a.w * sc);
        pk.u[2] = pk2(b.x * sc, b.y * sc);
        pk.u[3] = pk2(b.z * sc, b.w * sc);
        qf[ks] = pk.v;
    }

    f32x16 acc[4];
#pragma unroll
    for (int dt = 0; dt < 4; ++dt)
#pragma unroll
        for (int r = 0; r < 16; ++r) acc[dt][r] = 0.f;
    float rowsum = 0.f;

    // ---- staging: global (bf16 images) -> regs -> swizzled LDS ----
    s16x8 kst[2], vst[2];
    auto stage_load = [&](int t) {
        const s16x8* kt = (const s16x8*)(Kimg + (size_t)(tile0 + t) * 8192);
        const s16x8* vt = (const s16x8*)(VTimg + (size_t)(tile0 + t) * 8192);
#pragma unroll
        for (int j = 0; j < 2; ++j) {
            kst[j] = kt[j * 512 + tid];
            vst[j] = vt[j * 512 + tid];
        }
    };
    auto stage_write = [&](int buf) {
#pragma unroll
        for (int j = 0; j < 2; ++j) {
            int ch = j * 512 + tid;
            int row = ch >> 4, c16 = ch & 15;
            *(s16x8*)((char*)sK[buf] + row * 256 + 16 * (c16 ^ (row & 15))) = kst[j];
            *(s16x8*)((char*)sV[buf] + row * 256 + 16 * ((c16 + row) & 15)) = vst[j];
        }
    };

    stage_load(0);
    stage_write(0);
    __syncthreads();

    for (int tile = 0; tile < NT; ++tile) {
        const int cur = tile & 1;
        const bool pf = (tile + 1 < NT);
        if (pf) stage_load(tile + 1);       // issue early; lands under compute

        const u16* bK = sK[cur];
        const u16* bV = sV[cur];

#pragma unroll
        for (int ct = 0; ct < 2; ++ct) {
            const char* krow = (const char*)bK + (32 * ct + ln5) * 256;
            // ---- S^T = K Qn^T over d=128, two interleaved partial chains ----
            f32x16 sa, sb;
#pragma unroll
            for (int r = 0; r < 16; ++r) { sa[r] = 0.f; sb[r] = 0.f; }
            __builtin_amdgcn_s_setprio(1);
#pragma unroll
            for (int ks = 0; ks < 8; ks += 2) {
                s16x8 kf0 = *(const s16x8*)(krow + 16 * ((2 * ks + h) ^ (ln5 & 15)));
                s16x8 kf1 = *(const s16x8*)(krow + 16 * ((2 * ks + 2 + h) ^ (ln5 & 15)));
                sa = __builtin_amdgcn_mfma_f32_32x32x16_bf16(kf0, qf[ks], sa, 0, 0, 0);
                sb = __builtin_amdgcn_mfma_f32_32x32x16_bf16(kf1, qf[ks + 1], sb, 0, 0, 0);
            }
            __builtin_amdgcn_s_setprio(0);

            // ---- P = exp2(sa+sb); half-exchange via shfl (proven 0-conflict) ----
            unsigned d0[4], d1[4], s0[4], s1[4];
#pragma unroll
            for (int m = 0; m < 4; ++m) {
                float p0 = exp2_hw(sa[4 * m + 0] + sb[4 * m + 0]);
                float p1 = exp2_hw(sa[4 * m + 1] + sb[4 * m + 1]);
                float p2 = exp2_hw(sa[4 * m + 2] + sb[4 * m + 2]);
                float p3 = exp2_hw(sa[4 * m + 3] + sb[4 * m + 3]);
                rowsum += (p0 + p1) + (p2 + p3);
                d0[m] = pk2(p0, p1);
                d1[m] = pk2(p2, p3);
            }
#pragma unroll
            for (int m = 0; m < 4; ++m) {
                s0[m] = (unsigned)__shfl_xor((int)d0[m], 32);
                s1[m] = (unsigned)__shfl_xor((int)d1[m], 32);
            }

            // ---- O += P V ----
#pragma unroll
            for (int kt2 = 0; kt2 < 2; ++kt2) {
                union { unsigned u[4]; s16x8 v; } Au;
                Au.u[0] = h ? s0[2 * kt2 + 1] : d0[2 * kt2];
                Au.u[1] = h ? s1[2 * kt2 + 1] : d1[2 * kt2];
                Au.u[2] = h ? d0[2 * kt2 + 1] : s0[2 * kt2];
                Au.u[3] = h ? d1[2 * kt2 + 1] : s1[2 * kt2];
                const int ktg = 2 * ct + kt2;
                const int ccv = (8 * (ln5 & 1) + 2 * ktg + h + (ln5 >> 1)) & 15;
                __builtin_amdgcn_s_setprio(1);
#pragma unroll
                for (int dt = 0; dt < 4; ++dt) {
                    s16x8 vf = *(const s16x8*)((const char*)bV +
                                               (16 * dt + (ln5 >> 1)) * 256 + 16 * ccv);
                    acc[dt] = __builtin_amdgcn_mfma_f32_32x32x16_bf16(Au.v, vf, acc[dt], 0, 0, 0);
                }
                __builtin_amdgcn_s_setprio(0);
            }
        }

        if (pf) stage_write(cur ^ 1);       // write late (T14), then one barrier
        __syncthreads();
    }

    // ---- epilogue: combine partials via device-scope atomics ----
    float tot = rowsum + __shfl_xor(rowsum, 32);
    if (h == 0) atomicAdd(&denom[q], tot);
#pragma unroll
    for (int dt = 0; dt < 4; ++dt)
#pragma unroll
        for (int r = 0; r < 16; ++r) {
            int qr = qrow0 + 32 * w + (r & 3) + 8 * (r >> 2) + 4 * h;
            atomicAdd(&num[(size_t)qr * D + 32 * dt + ln5], acc[dt][r]);
        }
}

// ---------------- finalize: y = 2x - num/denom ; LayerNorm ----------------
__global__ __launch_bounds__(256) void finalize(const float* __restrict__ x,
                                                const float* __restrict__ gamma,
                                                const float* __restrict__ beta,
                                                const float* __restrict__ denom,
                                                float* __restrict__ out) {  // out == num, in place
    int t = threadIdx.x;
    int row = blockIdx.x * 64 + (t >> 2);
    int q = t & 3;
    float invd = 1.0f / denom[row];
    const float4* xr = (const float4*)(x + (size_t)row * D);
    const float4* nr = (const float4*)(out + (size_t)row * D);
    float y[32];
    float s1 = 0.f, s2 = 0.f;
#pragma unroll
    for (int i = 0; i < 8; ++i) {
        float4 xv = xr[q * 8 + i];
        float4 nv = nr[q * 8 + i];
#pragma unroll
        for (int j = 0; j < 4; ++j) {
            float yv = (1.0f + SCALE) * (&xv.x)[j] - SCALE * ((&nv.x)[j] * invd);
            y[i * 4 + j] = yv;
            s1 += yv;
            s2 += yv * yv;
        }
    }
    s1 += __shfl_xor(s1, 1); s1 += __shfl_xor(s1, 2);
    s2 += __shfl_xor(s2, 1); s2 += __shfl_xor(s2, 2);
    float mu = s1 * (1.0f / D);
    float var = s2 * (1.0f / D) - mu * mu;
    float rstd = rsqrtf(var + LN_EPS);
    float4* orow = (float4*)(out + (size_t)row * D);
#pragma unroll
    for (int i = 0; i < 8; ++i) {
        int c = q * 32 + i * 4;
        float4 o;
#pragma unroll
        for (int j = 0; j < 4; ++j)
            (&o.x)[j] = (y[i * 4 + j] - mu) * rstd * gamma[c + j] + beta[c + j];
        orow[q * 8 + i] = o;
    }
}

extern "C" void kernel_launch(void* const* d_in, const int* in_sizes, int n_in,
                              void* d_out, int out_size, void* d_ws, size_t ws_size,
                              hipStream_t stream) {
    const float* x = (const float*)d_in[0];
    const float* gamma = (const float*)d_in[1];
    const float* beta = (const float*)d_in[2];
    float* out = (float*)d_out;

    float* invnrm = (float*)d_ws;                       // 64 KB
    float* denom = invnrm + N_ROWS;                     // 64 KB
    u16* Kimg = (u16*)(denom + N_ROWS);                 // 4 MB
    u16* VTimg = Kimg + (size_t)NTILES * 8192;          // 4 MB  (total ~8.4 MB)

    (void)hipMemsetAsync(d_out, 0, (size_t)N_ROWS * D * sizeof(float), stream);  // num accumulator
    (void)hipMemsetAsync(denom, 0, (size_t)N_ROWS * sizeof(float), stream);

    prep_norms<<<N_ROWS / 64, 256, 0, stream>>>(x, invnrm);
    prep_imgK<<<NTILES * 4, 256, 0, stream>>>(x, invnrm, Kimg);
    prep_imgVT<<<NTILES, 256, 0, stream>>>(x, VTimg);
    attn<<<(N_ROWS / QBLK) * NSPLIT, 512, 0, stream>>>(x, Kimg, VTimg, invnrm, out, denom);
    finalize<<<N_ROWS / 64, 256, 0, stream>>>(x, gamma, beta, denom, out);
}